// Round 3
// baseline (1213.686 us; speedup 1.0000x reference)
//
#include <hip/hip_runtime.h>
#include <hip/hip_bf16.h>

typedef __hip_bfloat16 bf16;
typedef float f32x2 __attribute__((ext_vector_type(2)));

#define NB_B 4
#define N 20000
#define E 640000
#define F 64
#define HC 128   // conv1 heads*ch
#define ED 16
#define CH 16
#define NT 32    // nodes per tile in node-transform kernels

__device__ __forceinline__ float clampf(float v, float lo, float hi){ return fminf(fmaxf(v, lo), hi); }
__device__ __forceinline__ float ldv(const float* p, size_t i){ return p[i]; }
__device__ __forceinline__ float ldv(const bf16*  p, size_t i){ return __bfloat162float(p[i]); }
__device__ __forceinline__ void  stv(float* p, size_t i, float v){ p[i] = v; }
__device__ __forceinline__ void  stv(bf16*  p, size_t i, float v){ p[i] = __float2bfloat16(v); }
__device__ __forceinline__ unsigned short tobf(float v){ bf16 b = __float2bfloat16(v); return *(unsigned short*)&b; }
__device__ __forceinline__ float unpl(unsigned u){ return __uint_as_float(u << 16); }
__device__ __forceinline__ float unph(unsigned u){ return __uint_as_float(u & 0xffff0000u); }
__device__ __forceinline__ f32x2 mk2(float a, float b){ f32x2 r; r.x = a; r.y = b; return r; }
__device__ __forceinline__ int rfl(int v){ return __builtin_amdgcn_readfirstlane(v); }

#define L2E 1.44269504f

// 16-lane (DPP row) all-reduce sum: pure VALU (row_ror butterfly 8,4,2,1).
__device__ __forceinline__ float rsum16(float x){
  x += __int_as_float(__builtin_amdgcn_update_dpp(0, __float_as_int(x), 0x128, 0xf, 0xf, true));
  x += __int_as_float(__builtin_amdgcn_update_dpp(0, __float_as_int(x), 0x124, 0xf, 0xf, true));
  x += __int_as_float(__builtin_amdgcn_update_dpp(0, __float_as_int(x), 0x122, 0xf, 0xf, true));
  x += __int_as_float(__builtin_amdgcn_update_dpp(0, __float_as_int(x), 0x121, 0xf, 0xf, true));
  return x;
}

// ---------------- dtype detector: f32 inputs (flag=1) vs bf16 (flag=0) ----------------
__global__ __launch_bounds__(256) void k_detect(const unsigned short* __restrict__ xu, int* __restrict__ flag){
  __shared__ int cnt[256];
  int tid = threadIdx.x;
  unsigned short lo = xu[2*tid];
  bf16 h = *(const bf16*)&lo;
  float v = fabsf(__bfloat162float(h));
  cnt[tid] = (v > 1e4f || (v != 0.f && v < 1e-4f)) ? 1 : 0;
  __syncthreads();
  for (int s=128; s>0; s>>=1){ if (tid<s) cnt[tid]+=cnt[tid+s]; __syncthreads(); }
  if (tid==0) *flag = (cnt[0] > 64) ? 1 : 0;
}

// ---------------- CSR build: histogram -> scan -> scatter(+ea reorder) ----------------
__global__ __launch_bounds__(256) void k_hist(const int* __restrict__ ei, int* __restrict__ cnt, int b0){
  int z = blockIdx.z, b = b0 + z;
  int e = blockIdx.x*256 + threadIdx.x;
  int d = ei[((size_t)b*2+1)*E + e];
  atomicAdd(&cnt[z*N + d], 1);
}

__global__ __launch_bounds__(256) void k_scan(const int* __restrict__ cnt, int* __restrict__ rowptr,
                                              int* __restrict__ cursor){
  int z = blockIdx.z, tid = threadIdx.x;
  const int* c = cnt + (size_t)z*N;
  int* rp = rowptr + (size_t)z*(N+1);
  int* cu = cursor + (size_t)z*N;
  const int CHK = (N + 255)/256;
  int lo = tid*CHK; int hi = lo + CHK; if (hi > N) hi = N; if (lo > N) lo = N;
  int s = 0;
  for (int i=lo;i<hi;i++) s += c[i];
  __shared__ int buf[256];
  buf[tid] = s; __syncthreads();
  for (int off=1; off<256; off<<=1){
    int t = (tid>=off) ? buf[tid-off] : 0;
    __syncthreads();
    buf[tid] += t;
    __syncthreads();
  }
  int run = buf[tid] - s;         // exclusive prefix
  for (int i=lo;i<hi;i++){ int v=c[i]; rp[i]=run; cu[i]=run; run += v; }
  if (tid==255) rp[N] = run;
}

// scatter: write src index + copy edge attrs into CSR order (f32, numerically identical).
template<typename T>
__device__ __forceinline__ void scatter_body(const int* ei, int* cursor, int* csr,
                                             const T* ea, float* eacsr, int b0){
  int z = blockIdx.z, b = b0 + z;
  int e = blockIdx.x*256 + threadIdx.x;
  int s = ei[((size_t)b*2+0)*E + e];
  int d = ei[((size_t)b*2+1)*E + e];
  int pos = atomicAdd(&cursor[z*N + d], 1);
  csr[(size_t)z*E + pos] = s;
  float4* dst = (float4*)(eacsr + ((size_t)z*E + pos)*ED);
  const T* sp = ea + ((size_t)b*E + e)*ED;
  #pragma unroll
  for (int g=0; g<4; g++){
    float4 t;
    t.x = ldv(sp, g*4+0); t.y = ldv(sp, g*4+1); t.z = ldv(sp, g*4+2); t.w = ldv(sp, g*4+3);
    dst[g] = t;
  }
}
__global__ __launch_bounds__(256) void k_scatter(const int* ei, int* cursor, int* csr,
    const void* ea, float* eacsr, const int* flag, int b0){
  if (*flag) scatter_body(ei, cursor, csr, (const float*)ea, eacsr, b0);
  else       scatter_body(ei, cursor, csr, (const bf16*) ea, eacsr, b0);
}

// ---------------- conv1 node transform: 32-node tile, writes packed bf16 directly ----------------
template<typename T>
__device__ __forceinline__ void node1_body(const T* x, const T* Wl, const T* Wr,
                                           unsigned* xl1p, unsigned* xr1p, int b0,
                                           float (*xs)[F+4]){
  int z = blockIdx.z, b = b0 + z;
  int node0 = blockIdx.x*NT;
  for (int i=threadIdx.x; i<NT*F; i+=256){
    int n = i>>6, k = i&63;
    xs[n][k] = ldv(x, ((size_t)b*N + node0 + n)*F + k);
  }
  __syncthreads();
  int mat = threadIdx.x >> 7, c = threadIdx.x & 127;
  const T* W = mat ? Wr : Wl;
  float acc[NT];
  #pragma unroll
  for (int n=0;n<NT;n++) acc[n]=0.f;
  for (int k=0;k<F;k+=4){
    float w0 = ldv(W, (size_t)(k+0)*HC + c);
    float w1 = ldv(W, (size_t)(k+1)*HC + c);
    float w2 = ldv(W, (size_t)(k+2)*HC + c);
    float w3 = ldv(W, (size_t)(k+3)*HC + c);
    #pragma unroll
    for (int n=0;n<NT;n++){
      float4 xv = *(const float4*)&xs[n][k];
      acc[n] += xv.x*w0 + xv.y*w1 + xv.z*w2 + xv.w*w3;
    }
  }
  unsigned short* outp = (unsigned short*)(mat ? xr1p : xl1p);
  int half = c>>6, cc = c&63;
  #pragma unroll
  for (int n=0;n<NT;n++){
    float v = clampf(acc[n], -1e4f, 1e4f);
    outp[(((size_t)z*N + node0 + n)*64 + cc)*2 + half] = tobf(v);
  }
}
__global__ __launch_bounds__(256) void k_node1(const void* x, const void* Wl, const void* Wr,
    unsigned* xl1p, unsigned* xr1p, const int* flag, int b0){
  __shared__ float xs[NT][F+4];
  if (*flag) node1_body((const float*)x,(const float*)Wl,(const float*)Wr,xl1p,xr1p,b0,xs);
  else       node1_body((const bf16*) x,(const bf16*) Wl,(const bf16*) Wr,xl1p,xr1p,b0,xs);
}

// ---------------- conv1 fused gather: wave-per-node, scalar (SGPR) edge streams ----------------
// node/rs/re/src/ev are wave-uniform -> readfirstlane-hoisted so csr + eacsr stream through
// scalar loads; no LDS at all; gathered xl1p word is the only per-lane load.
template<typename T>
__device__ __forceinline__ void gather1_body(const int* __restrict__ rowptr, const int* __restrict__ csr,
    const float* __restrict__ eacsr, const T* __restrict__ We, const T* __restrict__ att, const T* __restrict__ b1,
    const unsigned* __restrict__ xl1p, const unsigned* __restrict__ xr1p, float* __restrict__ hx, int b0){
  int z = blockIdx.z;
  int lane = threadIdx.x & 63;
  int node = rfl(blockIdx.x*4 + (threadIdx.x >> 6));
  int rs = rfl(rowptr[(size_t)z*(N+1) + node]);
  int re = rfl(rowptr[(size_t)z*(N+1) + node + 1]);
  f32x2 w[ED];
  #pragma unroll
  for (int j=0;j<ED;j++) w[j] = mk2(ldv(We,(size_t)j*HC+lane), ldv(We,(size_t)j*HC+lane+64));
  f32x2 attv = mk2(ldv(att,(size_t)lane)*L2E, ldv(att,(size_t)lane+64)*L2E);
  unsigned xru = xr1p[((size_t)z*N + node)*64 + lane];
  f32x2 xr2 = mk2(unpl(xru), unph(xru));
  f32x2 acc = mk2(0.f,0.f), den = mk2(0.f,0.f);
  const unsigned* __restrict__ xlp = xl1p + (size_t)z*N*64;
  const int* __restrict__ csrz = csr + (size_t)z*E + rs;
  const float* __restrict__ eaz = eacsr + ((size_t)z*E + rs)*ED;
  int deg = re - rs;
  if (deg > 0){
    int s0 = rfl(csrz[0]);
    int s1 = (deg>1) ? rfl(csrz[1]) : s0;
    unsigned xa = xlp[(size_t)(unsigned)s0*64 + lane];
    unsigned xb = xlp[(size_t)(unsigned)s1*64 + lane];
    #pragma unroll 2
    for (int i=0;i<deg;i++){
      const float* __restrict__ ep = eaz + (size_t)i*ED;
      float ev[ED];
      #pragma unroll
      for (int j=0;j<ED;j++) ev[j] = ep[j];          // wave-uniform -> s_load stream
      unsigned xw = xa;
      xa = xb;
      if (i+2 < deg){
        int sn = rfl(csrz[i+2]);
        xb = xlp[(size_t)(unsigned)sn*64 + lane];
      }
      f32x2 xl = mk2(unpl(xw), unph(xw));
      f32x2 g0 = xl + xr2, g1 = mk2(0.f,0.f);
      #pragma unroll
      for (int j=0;j<ED;j+=2){ g0 += w[j]*ev[j]; g1 += w[j+1]*ev[j+1]; }
      f32x2 g = g0 + g1;
      f32x2 lr;
      lr.x = fmaxf(g.x,0.f) + 0.2f*fminf(g.x,0.f);
      lr.y = fmaxf(g.y,0.f) + 0.2f*fminf(g.y,0.f);
      f32x2 v = lr*attv;
      float vL = rsum16(v.x);
      float vH = rsum16(v.y);
      f32x2 ex = mk2(exp2f(clampf(vL,-86.f,86.f)), exp2f(clampf(vH,-86.f,86.f)));
      den += ex;
      acc += ex*xl;
    }
  }
  float hL = acc.x/(den.x + 1e-16f) + ldv(b1,(size_t)lane);
  float hH = acc.y/(den.y + 1e-16f) + ldv(b1,(size_t)lane+64);
  hL = hL>0.f ? hL : expm1f(hL);
  hH = hH>0.f ? hH : expm1f(hH);
  hx[((size_t)z*N + node)*HC + lane]      = hL;
  hx[((size_t)z*N + node)*HC + lane + 64] = hH;
}
__global__ __launch_bounds__(256) void k_gather1(const int* __restrict__ rowptr, const int* __restrict__ csr,
    const float* __restrict__ eacsr,
    const void* We, const void* att, const void* b1,
    const unsigned* __restrict__ xl1p, const unsigned* __restrict__ xr1p, float* __restrict__ hx,
    const int* __restrict__ flag, int b0){
  if (*flag) gather1_body(rowptr,csr,eacsr,(const float*)We,(const float*)att,(const float*)b1,xl1p,xr1p,hx,b0);
  else       gather1_body(rowptr,csr,eacsr,(const bf16*) We,(const bf16*) att,(const bf16*) b1,xl1p,xr1p,hx,b0);
}

// ---------------- conv2/conv3 node transforms: 32-node tile, writes packed bf16 directly ----------------
template<typename T>
__device__ __forceinline__ void node2_body(const float* hx, const unsigned* xl1p,
    const T* W2l, const T* W2r, const T* W3l, const T* W3r,
    unsigned* xl23p, unsigned* xr23p, int b0,
    float (*hv)[HC+4], float (*sv)[HC+4]){
  int z = blockIdx.z;
  int node0 = blockIdx.x*NT;
  for (int i=threadIdx.x; i<NT*HC; i+=256){
    int n = i>>7, k = i&127;
    float h = hx[((size_t)z*N + node0 + n)*HC + k];
    unsigned wxl = xl1p[((size_t)z*N + node0 + n)*64 + (k&63)];
    float xv = (k<64) ? unpl(wxl) : unph(wxl);
    hv[n][k] = h;
    sv[n][k] = h + xv;                // hs = hx + skip(=xl1)
  }
  __syncthreads();
  int o = threadIdx.x & 63;
  int mat = o >> 4, c = o & 15;
  int g = threadIdx.x >> 6;
  const T* W = (mat==0)? W2l : (mat==1)? W2r : (mat==2)? W3l : W3r;
  float (*src)[HC+4] = (mat<2)? hv : sv;
  float acc[8];
  #pragma unroll
  for (int j=0;j<8;j++) acc[j]=0.f;
  for (int k=0;k<HC;k+=4){
    float w0 = ldv(W, (size_t)(k+0)*CH + c);
    float w1 = ldv(W, (size_t)(k+1)*CH + c);
    float w2 = ldv(W, (size_t)(k+2)*CH + c);
    float w3 = ldv(W, (size_t)(k+3)*CH + c);
    #pragma unroll
    for (int j=0;j<8;j++){
      float4 xv = *(const float4*)&src[g*8+j][k];
      acc[j] += xv.x*w0 + xv.y*w1 + xv.z*w2 + xv.w*w3;
    }
  }
  unsigned short* arr = (unsigned short*)((mat&1) ? xr23p : xl23p);
  int half = mat>>1;
  #pragma unroll
  for (int j=0;j<8;j++){
    float v = clampf(acc[j], -1e4f, 1e4f);
    arr[(((size_t)z*N + node0 + g*8 + j)*CH + c)*2 + half] = tobf(v);
  }
}
__global__ __launch_bounds__(256) void k_node2(const float* hx, const unsigned* xl1p,
    const void* W2l, const void* W2r, const void* W3l, const void* W3r,
    unsigned* xl23p, unsigned* xr23p, const int* flag, int b0){
  __shared__ float hv[NT][HC+4];
  __shared__ float sv[NT][HC+4];
  if (*flag) node2_body(hx,xl1p,(const float*)W2l,(const float*)W2r,(const float*)W3l,(const float*)W3r,xl23p,xr23p,b0,hv,sv);
  else       node2_body(hx,xl1p,(const bf16*) W2l,(const bf16*) W2r,(const bf16*) W3l,(const bf16*) W3r,xl23p,xr23p,b0,hv,sv);
}

// ---------------- conv2+conv3 fused gather + linear + LayerNorm + store ----------------
// Wave-per-node: 64 lanes = 16 channels x 4 edges in parallel (groups). No LDS, no divergence;
// group partials combined once per node via shfl_xor(16/32).
template<typename T>
__device__ __forceinline__ void gather23_body(const int* __restrict__ rowptr, const int* __restrict__ csr,
    const float* __restrict__ eacsr,
    const T* __restrict__ We2, const T* __restrict__ We3, const T* __restrict__ att2, const T* __restrict__ att3,
    const T* __restrict__ b2, const T* __restrict__ b3, const T* __restrict__ linW, const T* __restrict__ linb,
    const T* __restrict__ lng, const T* __restrict__ lnb,
    const unsigned* __restrict__ xl23p, const unsigned* __restrict__ xr23p,
    T* __restrict__ out, int b0){
  int z = blockIdx.z;
  int lane = threadIdx.x & 63;
  int g = lane >> 4, c = lane & 15;
  int node = rfl(blockIdx.x*4 + (threadIdx.x >> 6));
  int rs = rfl(rowptr[(size_t)z*(N+1) + node]);
  int re = rfl(rowptr[(size_t)z*(N+1) + node + 1]);
  int deg = re - rs;
  f32x2 w[ED];
  #pragma unroll
  for (int j=0;j<ED;j++) w[j] = mk2(ldv(We2,(size_t)j*CH+c), ldv(We3,(size_t)j*CH+c));
  f32x2 attv = mk2(ldv(att2,(size_t)c)*L2E, ldv(att3,(size_t)c)*L2E);
  unsigned xru = xr23p[((size_t)z*N + node)*CH + c];
  f32x2 xr2 = mk2(unpl(xru), unph(xru));
  f32x2 acc = mk2(0.f,0.f), den = mk2(0.f,0.f);
  const unsigned* __restrict__ xlp = xl23p + (size_t)z*N*CH;
  const int* __restrict__ csrz = csr + (size_t)z*E + rs;
  const float* __restrict__ eaz = eacsr + ((size_t)z*E + rs)*ED;
  if (deg > 0){
    int idx0 = (g < deg) ? g : deg-1;
    int s = csrz[idx0];
    unsigned xw = xlp[(size_t)(unsigned)s*CH + c];
    const float4* p0 = (const float4*)(eaz + (size_t)idx0*ED);
    float4 e0 = p0[0], e1 = p0[1], e2 = p0[2], e3 = p0[3];
    for (int i=0;i<deg;i+=4){
      bool act = (i + g) < deg;
      unsigned xcur = xw;
      float4 c0 = e0, c1 = e1, c2 = e2, c3 = e3;
      if (i+4 < deg){                                  // prefetch next step
        int ii = i + 4 + g;
        int idx = (ii < deg) ? ii : deg-1;
        int s2 = csrz[idx];
        xw = xlp[(size_t)(unsigned)s2*CH + c];
        const float4* p2 = (const float4*)(eaz + (size_t)idx*ED);
        e0 = p2[0]; e1 = p2[1]; e2 = p2[2]; e3 = p2[3];
      }
      float ev[ED];
      *(float4*)&ev[0]  = c0;
      *(float4*)&ev[4]  = c1;
      *(float4*)&ev[8]  = c2;
      *(float4*)&ev[12] = c3;
      f32x2 xl = mk2(unpl(xcur), unph(xcur));
      f32x2 g0 = xl + xr2, g1 = mk2(0.f,0.f);
      #pragma unroll
      for (int j=0;j<ED;j+=2){ g0 += w[j]*ev[j]; g1 += w[j+1]*ev[j+1]; }
      f32x2 gg = g0 + g1;
      f32x2 lr;
      lr.x = fmaxf(gg.x,0.f) + 0.2f*fminf(gg.x,0.f);
      lr.y = fmaxf(gg.y,0.f) + 0.2f*fminf(gg.y,0.f);
      f32x2 v = lr*attv;
      float v2 = rsum16(v.x);
      float v3 = rsum16(v.y);
      float x2e = exp2f(clampf(v2,-86.f,86.f));
      float x3e = exp2f(clampf(v3,-86.f,86.f));
      if (!act){ x2e = 0.f; x3e = 0.f; }
      f32x2 ex = mk2(x2e, x3e);
      den += ex;
      acc += ex*xl;
    }
  }
  // combine group partials (lanes {c, 16+c, 32+c, 48+c})
  acc.x += __shfl_xor(acc.x, 16); acc.x += __shfl_xor(acc.x, 32);
  acc.y += __shfl_xor(acc.y, 16); acc.y += __shfl_xor(acc.y, 32);
  den.x += __shfl_xor(den.x, 16); den.x += __shfl_xor(den.x, 32);
  den.y += __shfl_xor(den.y, 16); den.y += __shfl_xor(den.y, 32);
  float x1 = acc.x/(den.x + 1e-16f) + ldv(b2,(size_t)c);   // conv2 output
  float x3 = acc.y/(den.y + 1e-16f) + ldv(b3,(size_t)c);   // skip-conv output
  float x2 = 0.f;
  #pragma unroll
  for (int j=0;j<16;j++) x2 += __shfl(x3, j, 16) * ldv(linW, (size_t)c*16 + j);
  x2 += ldv(linb,(size_t)c);
  float y = clampf(x1, -1e6f, 1e6f) + clampf(x2, -1e6f, 1e6f);
  float mu = rsum16(y)*(1.f/16.f);
  float dv = y - mu;
  float var = rsum16(dv*dv)*(1.f/16.f);
  float o = dv*rsqrtf(var + 1e-5f)*ldv(lng,(size_t)c) + ldv(lnb,(size_t)c);
  if (lane < 16) stv(out, ((size_t)(b0+z)*N + node)*16 + c, o);
}
__global__ __launch_bounds__(256) void k_gather23(const int* __restrict__ rowptr, const int* __restrict__ csr,
    const float* __restrict__ eacsr,
    const void* We2, const void* We3, const void* att2, const void* att3,
    const void* b2, const void* b3, const void* linW, const void* linb, const void* lng, const void* lnb,
    const unsigned* __restrict__ xl23p, const unsigned* __restrict__ xr23p,
    void* out, const int* __restrict__ flag, int b0){
  if (*flag) gather23_body(rowptr,csr,eacsr,(const float*)We2,(const float*)We3,(const float*)att2,(const float*)att3,
                           (const float*)b2,(const float*)b3,(const float*)linW,(const float*)linb,(const float*)lng,(const float*)lnb,
                           xl23p,xr23p,(float*)out,b0);
  else       gather23_body(rowptr,csr,eacsr,(const bf16*) We2,(const bf16*) We3,(const bf16*) att2,(const bf16*) att3,
                           (const bf16*) b2,(const bf16*) b3,(const bf16*) linW,(const bf16*) linb,(const bf16*) lng,(const bf16*) lnb,
                           xl23p,xr23p,(bf16*) out,b0);
}

// ---------------- workspace layout ----------------
struct WSP {
  int* flag;
  int *cnt, *cursor, *rowptr; int* csr;
  float *eacsr, *hx;
  unsigned *xl1p,*xr1p,*xl23p,*xr23p;
  size_t total;
};
static WSP mkws(char* base, int nb){
  WSP w; size_t off = 0;
  auto A = [&](size_t bytes)->char*{ char* p = base ? base + off : (char*)0; off = (off + bytes + 255) & ~(size_t)255; return p; };
  w.flag   = (int*)     A(256);
  w.cnt    = (int*)     A((size_t)nb*N*4);
  w.cursor = (int*)     A((size_t)nb*N*4);
  w.rowptr = (int*)     A((size_t)nb*(N+1)*4);
  w.csr    = (int*)     A((size_t)nb*E*4);
  w.eacsr  = (float*)   A((size_t)nb*E*ED*4);
  w.hx     = (float*)   A((size_t)nb*N*HC*4);
  w.xl1p   = (unsigned*)A((size_t)nb*N*64*4);
  w.xr1p   = (unsigned*)A((size_t)nb*N*64*4);
  w.xl23p  = (unsigned*)A((size_t)nb*N*CH*4);
  w.xr23p  = (unsigned*)A((size_t)nb*N*CH*4);
  w.total = off;
  return w;
}

extern "C" void kernel_launch(void* const* d_in, const int* in_sizes, int n_in,
                              void* d_out, int out_size, void* d_ws, size_t ws_size,
                              hipStream_t stream){
  const void* x    = d_in[0];
  const void* ea   = d_in[1];
  const int*  ei   = (const int*)d_in[2];
  const void* c1Wl = d_in[3], *c1Wr = d_in[4], *c1We = d_in[5];
  const void* c1att= d_in[6], *c1b  = d_in[7];
  const void* c2Wl = d_in[8], *c2Wr = d_in[9], *c2We = d_in[10];
  const void* c2att= d_in[11],*c2b  = d_in[12];
  const void* sWl  = d_in[13],*sWr  = d_in[14],*sWe  = d_in[15];
  const void* satt = d_in[16],*sb   = d_in[17];
  const void* linW = d_in[18],*linb = d_in[19];
  const void* lng  = d_in[20],*lnb  = d_in[21];

  auto run = [&](int b0, int nb){
    WSP w = mkws((char*)d_ws, nb);
    hipMemsetAsync(w.cnt, 0, (size_t)nb*N*4, stream);
    k_hist   <<<dim3(E/256,1,nb),   256,0,stream>>>(ei, w.cnt, b0);
    k_scan   <<<dim3(1,1,nb),       256,0,stream>>>(w.cnt, w.rowptr, w.cursor);
    k_scatter<<<dim3(E/256,1,nb),   256,0,stream>>>(ei, w.cursor, w.csr, ea, w.eacsr, w.flag, b0);
    // conv1
    k_node1  <<<dim3(N/NT,1,nb),    256,0,stream>>>(x, c1Wl, c1Wr, w.xl1p, w.xr1p, w.flag, b0);
    k_gather1<<<dim3(N/4,1,nb),     256,0,stream>>>(w.rowptr, w.csr, w.eacsr, c1We, c1att, c1b,
                                                    w.xl1p, w.xr1p, w.hx, w.flag, b0);
    // conv2 + skip-conv
    k_node2  <<<dim3(N/NT,1,nb),    256,0,stream>>>(w.hx, w.xl1p, c2Wl, c2Wr, sWl, sWr,
                                                    w.xl23p, w.xr23p, w.flag, b0);
    k_gather23<<<dim3(N/4,1,nb),    256,0,stream>>>(w.rowptr, w.csr, w.eacsr, c2We, sWe, c2att, satt,
                                                    c2b, sb, linW, linb, lng, lnb,
                                                    w.xl23p, w.xr23p, d_out, w.flag, b0);
  };

  {
    WSP w0 = mkws((char*)d_ws, 1);
    k_detect<<<1,256,0,stream>>>((const unsigned short*)x, w0.flag);
  }

  WSP probe = mkws((char*)0, NB_B);
  if (ws_size >= probe.total){
    run(0, NB_B);                          // single batched pass
  } else {
    for (int g=0; g<NB_B; ++g) run(g, 1);  // per-graph fallback
  }
}